// Round 2
// baseline (942.124 us; speedup 1.0000x reference)
//
#include <hip/hip_runtime.h>

// 3-layer tanh-RNN, B=512, T=2048, D=6, H=32, fp32.
// Design: one block per batch element, 3 waves per block, one wave per LAYER.
// Wave l runs layer l's recurrence; cross-layer activations flow through
// double-buffered LDS ring buffers with a __syncthreads() every KS=4 steps.
// Pipeline skew: wave0 processes phase ph, wave1 phase ph-1, wave2 phase ph-2.
// Per-wave critical path per step: 16-FMA k-split dot -> cross-half combine
// -> tanh -> 16x ds_bpermute self-broadcast (~140 cy), vs ~650 cy for the
// single-wave 3-layer chain (three LDS round-trips) of the previous design.

#define T_LEN 2048
#define D_IN  6
#define KS    4                 // steps per phase (barrier period)
#define NPH   (T_LEN / KS)      // 512 phases

typedef float f4 __attribute__((ext_vector_type(4)));

// tanh(v) = 1 - 2/(e^{2v}+1); v_exp + v_rcp, ~1e-6 abs err, saturates correctly.
__device__ __forceinline__ float fast_tanh(float v) {
    float e = __expf(2.0f * v);
    return 1.0f - 2.0f / (e + 1.0f);
}

// cross-half (lane ^ 32) sum. NOTE: only lanes 0-31 strictly need the correct
// combined value (they feed all consumers); shfl_xor gives it to all 64.
__device__ __forceinline__ float xhalf_sum(float a) {
    return a + __shfl_xor(a, 32, 64);
}

__global__ void __launch_bounds__(192) rnn3_pipe(
    const float* __restrict__ x,     // [B, T, 6]
    const float* __restrict__ Wih0,  // [32, 6]
    const float* __restrict__ WihR,  // [2, 32, 32]
    const float* __restrict__ Whh,   // [3, 32, 32]
    const float* __restrict__ bih,   // [3, 32]
    const float* __restrict__ bhh,   // [3, 32]
    const float* __restrict__ fcw,   // [6, 32]
    const float* __restrict__ fcb,   // [6]
    float* __restrict__ out)         // [B, 6]
{
    const int b    = blockIdx.x;
    const int tid  = threadIdx.x;
    const int wid  = tid >> 6;      // 0,1,2 -> layer
    const int lane = tid & 63;
    const int j    = lane & 31;     // output index
    const int p    = lane >> 5;     // k-half

    __shared__ float ring1[2][KS][64];   // wave0 -> wave1
    __shared__ float ring2[2][KS][64];   // wave1 -> wave2
    __shared__ float h3fin[64];

    // ---- per-wave weights (one-time loads) ----
    float wh[16];     // recurrent row W_hh[wid][j][16p + i]
    float wi[16];     // input-proj row (waves 1,2)
    float w0x[D_IN];  // wave0 input row (full 6, applied after combine)
    float bs;
    {
        const f4* q = (const f4*)(Whh + wid * 1024 + j * 32 + 16 * p);
        f4 q0 = q[0], q1 = q[1], q2 = q[2], q3 = q[3];
#pragma unroll
        for (int i = 0; i < 4; ++i) { wh[i] = q0[i]; wh[4+i] = q1[i]; wh[8+i] = q2[i]; wh[12+i] = q3[i]; }
        bs = bih[wid * 32 + j] + bhh[wid * 32 + j];
        if (wid == 0) {
#pragma unroll
            for (int d = 0; d < D_IN; ++d) w0x[d] = Wih0[j * D_IN + d];
#pragma unroll
            for (int i = 0; i < 16; ++i) wi[i] = 0.0f;
        } else {
            const f4* qq = (const f4*)(WihR + (wid - 1) * 1024 + j * 32 + 16 * p);
            f4 a0 = qq[0], a1 = qq[1], a2 = qq[2], a3 = qq[3];
#pragma unroll
            for (int i = 0; i < 4; ++i) { wi[i] = a0[i]; wi[4+i] = a1[i]; wi[8+i] = a2[i]; wi[12+i] = a3[i]; }
#pragma unroll
            for (int d = 0; d < D_IN; ++d) w0x[d] = 0.0f;
        }
    }

    // self-broadcast recurrent state: hp[i] = h_wid(t-1)[16p + i]
    float hp[16];
#pragma unroll
    for (int i = 0; i < 16; ++i) hp[i] = 0.0f;

    const int bpbase = 64 * p;   // ds_bpermute byte addr of source lane 16p

    // wave0 x prefetch: one phase = KS*6 = 24 floats = 6 float4 (96B, 16B-aligned)
    const float* xg = x + (size_t)b * (T_LEN * D_IN);
    f4 xc[6], xn[6];
    if (wid == 0) {
        const f4* xp = (const f4*)xg;
#pragma unroll
        for (int m = 0; m < 6; ++m) xc[m] = xp[m];
    }

#pragma unroll 2                 // makes (ph & 1) compile-time per copy
    for (int ph = 0; ph < NPH + 2; ++ph) {
        if (wid == 0) {
            if (ph < NPH) {
                if (ph + 1 < NPH) {
                    const f4* xp = (const f4*)(xg + (ph + 1) * (KS * D_IN));
#pragma unroll
                    for (int m = 0; m < 6; ++m) xn[m] = xp[m];
                }
                // x-projections for the phase (off the recurrent chain)
                float xd[KS];
#pragma unroll
                for (int s = 0; s < KS; ++s) {
                    float acc = bs;
#pragma unroll
                    for (int d = 0; d < D_IN; ++d) {
                        const int e = s * D_IN + d;
                        acc += xc[e >> 2][e & 3] * w0x[d];
                    }
                    xd[s] = acc;
                }
#pragma unroll
                for (int s = 0; s < KS; ++s) {
                    float a0 = 0, a1 = 0, a2 = 0, a3 = 0;
#pragma unroll
                    for (int i = 0; i < 16; i += 4) {
                        a0 += hp[i]     * wh[i];
                        a1 += hp[i + 1] * wh[i + 1];
                        a2 += hp[i + 2] * wh[i + 2];
                        a3 += hp[i + 3] * wh[i + 3];
                    }
                    const float a = xhalf_sum((a0 + a1) + (a2 + a3));
                    const float h = fast_tanh(a + xd[s]);
                    ring1[ph & 1][s][lane] = h;
                    const int hu = __float_as_int(h);
#pragma unroll
                    for (int i = 0; i < 16; ++i)
                        hp[i] = __int_as_float(__builtin_amdgcn_ds_bpermute(bpbase + 4 * i, hu));
                }
#pragma unroll
                for (int m = 0; m < 6; ++m) xc[m] = xn[m];
            }
        } else if (wid == 1) {
            if (ph >= 1 && ph <= NPH) {
#pragma unroll
                for (int s = 0; s < KS; ++s) {
                    const f4* rp = (const f4*)&ring1[(ph - 1) & 1][s][16 * p];
                    f4 r0 = rp[0], r1 = rp[1], r2 = rp[2], r3 = rp[3];
                    float a0 = 0, a1 = 0, a2 = 0, a3 = 0;
#pragma unroll
                    for (int i = 0; i < 16; i += 4) {   // register part first
                        a0 += hp[i]     * wh[i];
                        a1 += hp[i + 1] * wh[i + 1];
                        a2 += hp[i + 2] * wh[i + 2];
                        a3 += hp[i + 3] * wh[i + 3];
                    }
#pragma unroll
                    for (int i = 0; i < 4; ++i) {
                        a0 += r0[i] * wi[i];
                        a1 += r1[i] * wi[4 + i];
                        a2 += r2[i] * wi[8 + i];
                        a3 += r3[i] * wi[12 + i];
                    }
                    const float a = xhalf_sum((a0 + a1) + (a2 + a3));
                    const float h = fast_tanh(a + bs);
                    ring2[(ph - 1) & 1][s][lane] = h;
                    const int hu = __float_as_int(h);
#pragma unroll
                    for (int i = 0; i < 16; ++i)
                        hp[i] = __int_as_float(__builtin_amdgcn_ds_bpermute(bpbase + 4 * i, hu));
                }
            }
        } else {
            if (ph >= 2) {
#pragma unroll
                for (int s = 0; s < KS; ++s) {
                    const f4* rp = (const f4*)&ring2[ph & 1][s][16 * p];
                    f4 r0 = rp[0], r1 = rp[1], r2 = rp[2], r3 = rp[3];
                    float a0 = 0, a1 = 0, a2 = 0, a3 = 0;
#pragma unroll
                    for (int i = 0; i < 16; i += 4) {
                        a0 += hp[i]     * wh[i];
                        a1 += hp[i + 1] * wh[i + 1];
                        a2 += hp[i + 2] * wh[i + 2];
                        a3 += hp[i + 3] * wh[i + 3];
                    }
#pragma unroll
                    for (int i = 0; i < 4; ++i) {
                        a0 += r0[i] * wi[i];
                        a1 += r1[i] * wi[4 + i];
                        a2 += r2[i] * wi[8 + i];
                        a3 += r3[i] * wi[12 + i];
                    }
                    const float a = xhalf_sum((a0 + a1) + (a2 + a3));
                    const float h = fast_tanh(a + bs);
                    h3fin[lane] = h;                    // last write = h3(T-1)
                    const int hu = __float_as_int(h);
#pragma unroll
                    for (int i = 0; i < 16; ++i)
                        hp[i] = __int_as_float(__builtin_amdgcn_ds_bpermute(bpbase + 4 * i, hu));
                }
            }
        }
        __syncthreads();
    }

    // ---- head: out[b] = h3(T-1) @ fc_w^T + fc_b (wave2 wrote h3fin, in-order) ----
    if (wid == 2 && lane < D_IN) {
        float acc = fcb[lane];
        const f4* fw = (const f4*)(fcw + lane * 32);
#pragma unroll
        for (int m = 0; m < 8; ++m) {
            f4 w4 = fw[m];
#pragma unroll
            for (int i = 0; i < 4; ++i) acc += h3fin[4 * m + i] * w4[i];
        }
        out[b * D_IN + lane] = acc;
    }
}

extern "C" void kernel_launch(void* const* d_in, const int* in_sizes, int n_in,
                              void* d_out, int out_size, void* d_ws, size_t ws_size,
                              hipStream_t stream) {
    const float* x    = (const float*)d_in[0];
    const float* Wih0 = (const float*)d_in[1];
    const float* WihR = (const float*)d_in[2];
    const float* Whh  = (const float*)d_in[3];
    const float* bih  = (const float*)d_in[4];
    const float* bhh  = (const float*)d_in[5];
    const float* fcw  = (const float*)d_in[6];
    const float* fcb  = (const float*)d_in[7];
    float* outp = (float*)d_out;

    const int B = in_sizes[0] / (T_LEN * D_IN);  // 512
    rnn3_pipe<<<B, 192, 0, stream>>>(x, Wih0, WihR, Whh, bih, bhh, fcw, fcb, outp);
}